// Round 10
// baseline (592.223 us; speedup 1.0000x reference)
//
#include <hip/hip_runtime.h>
#include <hip/hip_bf16.h>

// Problem constants: B=4, S=1024, F=1024, E=8, K=2, H=4*F=4096
constexpr int Ff = 1024;
constexpr int Ee = 8;
constexpr int Hh = 4096;
constexpr int T  = 4096;        // B*S tokens
constexpr int MBLK  = 40;       // 256-row m-blocks over padded row space (<=10240 rows)
constexpr int MB128 = 80;       // 128-row pack units

typedef short     bf16x8 __attribute__((ext_vector_type(8)));
typedef float     f32x4  __attribute__((ext_vector_type(4)));
typedef unsigned short u16x8 __attribute__((ext_vector_type(8)));

__device__ __forceinline__ float gelu_tanh(float v) {
  const float c = 0.7978845608028654f;  // sqrt(2/pi)
  float t = tanhf(c * (v + 0.044715f * v * v * v));
  return 0.5f * v * (1.0f + t);
}

__device__ __forceinline__ unsigned short bf16bits(float f) {
  __hip_bfloat16 h = __float2bfloat16(f);
  return *reinterpret_cast<unsigned short*>(&h);
}

__device__ __forceinline__ void gl_lds16(const void* g, void* l) {
  __builtin_amdgcn_global_load_lds(
      (const __attribute__((address_space(1))) unsigned int*)g,
      (__attribute__((address_space(3))) unsigned int*)l, 16, 0, 0);
}

// ---------------- Gating (fp32, exact routing) ----------------
__global__ __launch_bounds__(256) void gating_kernel(
    const float* __restrict__ x, const float* __restrict__ Wg,
    const float* __restrict__ bg, int* __restrict__ cnt,
    int* __restrict__ list, float* __restrict__ wlist) {
  const int wave = threadIdx.x >> 6;
  const int lane = threadIdx.x & 63;
  const int t = blockIdx.x * 4 + wave;
  float acc[Ee] = {0.f,0.f,0.f,0.f,0.f,0.f,0.f,0.f};
  const float* xrow = x + (size_t)t * Ff;
  for (int f0 = 0; f0 < Ff; f0 += 64) {
    float xv = xrow[f0 + lane];
    const float* wrow = Wg + (size_t)(f0 + lane) * Ee;
    float4 w0 = *reinterpret_cast<const float4*>(wrow);
    float4 w1 = *reinterpret_cast<const float4*>(wrow + 4);
    acc[0] += xv * w0.x; acc[1] += xv * w0.y;
    acc[2] += xv * w0.z; acc[3] += xv * w0.w;
    acc[4] += xv * w1.x; acc[5] += xv * w1.y;
    acc[6] += xv * w1.z; acc[7] += xv * w1.w;
  }
#pragma unroll
  for (int e = 0; e < Ee; ++e) {
#pragma unroll
    for (int off = 32; off; off >>= 1) acc[e] += __shfl_xor(acc[e], off);
  }
  if (lane == 0) {
    float l[Ee], m = -1e30f;
#pragma unroll
    for (int e = 0; e < Ee; ++e) { l[e] = acc[e] + bg[e]; m = fmaxf(m, l[e]); }
    float p[Ee], Z = 0.f;
#pragma unroll
    for (int e = 0; e < Ee; ++e) { p[e] = expf(l[e] - m); Z += p[e]; }
#pragma unroll
    for (int e = 0; e < Ee; ++e) p[e] /= Z;
    int i1 = 0; float p1 = p[0];
#pragma unroll
    for (int e = 1; e < Ee; ++e) if (p[e] > p1) { p1 = p[e]; i1 = e; }
    int i2 = -1; float p2 = -1e30f;
#pragma unroll
    for (int e = 0; e < Ee; ++e) if (e != i1 && p[e] > p2) { p2 = p[e]; i2 = e; }
    float denom = p1 + p2 + 1e-8f;
    int pos = atomicAdd(&cnt[i1], 1);
    list[i1 * T + pos] = t; wlist[i1 * T + pos] = p1 / denom;
    pos = atomicAdd(&cnt[i2], 1);
    list[i2 * T + pos] = t; wlist[i2 * T + pos] = p2 / denom;
  }
}

// 256-aligned expert row offsets (padded flattened row space)
__global__ void prefix_kernel(const int* __restrict__ cnt, int* __restrict__ offs) {
  if (threadIdx.x == 0) {
    int s = 0;
    for (int e = 0; e < Ee; ++e) { offs[e] = s; s += (cnt[e] + 255) & ~255; }
    offs[Ee] = s;
  }
}

// ---- pack_w: src fp32 [K][N] (stride sN) -> dst bf16 units [NB][KT][4][128][8]
__global__ __launch_bounds__(256) void pack_w_kernel(
    const float* __restrict__ src, unsigned short* __restrict__ dst,
    int sN, size_t s_estride, size_t d_estride, int KT) {
  const int e  = blockIdx.z;
  const int nb = blockIdx.x;
  const int kt = blockIdx.y;
  __shared__ float Ts[128][33];
  const int t = threadIdx.x;
  const float* sb = src + (size_t)e * s_estride + (size_t)(kt * 32) * sN + nb * 128;
  {
    const int row = t >> 5;
    const int cc  = (t & 31) * 4;
#pragma unroll
    for (int i = 0; i < 4; ++i) {
      float4 v = *reinterpret_cast<const float4*>(sb + (size_t)(row + 8 * i) * sN + cc);
      Ts[cc + 0][row + 8 * i] = v.x;
      Ts[cc + 1][row + 8 * i] = v.y;
      Ts[cc + 2][row + 8 * i] = v.z;
      Ts[cc + 3][row + 8 * i] = v.w;
    }
  }
  __syncthreads();
  unsigned short* db = dst + (size_t)e * d_estride + ((size_t)nb * KT + kt) * 4096;
#pragma unroll
  for (int j = 0; j < 2; ++j) {
    const int idx = t + 256 * j;
    const int col = idx & 127, kb = idx >> 7;
    u16x8 o;
#pragma unroll
    for (int q = 0; q < 8; ++q) o[q] = bf16bits(Ts[col][kb * 8 + q]);
    *reinterpret_cast<u16x8*>(db + kb * 1024 + col * 8) = o;
  }
}

// ---- pack_x: gather tokens -> xg[mb128][kt][4][128][8], zero-filled pads
__global__ __launch_bounds__(256) void pack_x_kernel(
    const float* __restrict__ x, const int* __restrict__ cnt,
    const int* __restrict__ offs, const int* __restrict__ list,
    unsigned short* __restrict__ xg) {
  const int kt = blockIdx.x;
  const int mb = blockIdx.y;
  const int t = threadIdx.x;
  const int m0g = mb * 128;
  int e = 0;
#pragma unroll
  for (int i = 1; i < Ee; ++i) e += (m0g >= offs[i]) ? 1 : 0;
  const int ce = cnt[e];
  const int row = t >> 1, half = t & 1;
  const int mloc = m0g - offs[e] + row;
  const bool valid = (mloc < ce);
  const int token = valid ? list[e * T + mloc] : 0;
  const float* sp = x + (size_t)token * Ff + kt * 32 + half * 16;
  u16x8 o0, o1;
#pragma unroll
  for (int i = 0; i < 2; ++i) {
    float4 v = valid ? *reinterpret_cast<const float4*>(sp + i * 4)
                     : make_float4(0.f, 0.f, 0.f, 0.f);
    o0[i * 4 + 0] = bf16bits(v.x); o0[i * 4 + 1] = bf16bits(v.y);
    o0[i * 4 + 2] = bf16bits(v.z); o0[i * 4 + 3] = bf16bits(v.w);
  }
#pragma unroll
  for (int i = 2; i < 4; ++i) {
    float4 v = valid ? *reinterpret_cast<const float4*>(sp + i * 4)
                     : make_float4(0.f, 0.f, 0.f, 0.f);
    o1[(i - 2) * 4 + 0] = bf16bits(v.x); o1[(i - 2) * 4 + 1] = bf16bits(v.y);
    o1[(i - 2) * 4 + 2] = bf16bits(v.z); o1[(i - 2) * 4 + 3] = bf16bits(v.w);
  }
  unsigned short* db = xg + ((size_t)mb * (Ff / 32) + kt) * 4096 + row * 8;
  *reinterpret_cast<u16x8*>(db + (half * 2 + 0) * 1024) = o0;
  *reinterpret_cast<u16x8*>(db + (half * 2 + 1) * 1024) = o1;
}

// ======== GEMM1: 256^2 tile, 8 waves, BK=32, depth-4 pipeline, 1 barrier/iter ========
__global__ __launch_bounds__(512, 2) void gemm1_mfma(
    const unsigned short* __restrict__ xg, const unsigned short* __restrict__ W1P,
    const float* __restrict__ b1, const int* __restrict__ cnt,
    const int* __restrict__ offs, unsigned short* __restrict__ hp, int Hc, int c) {
  const int nxg = Hc >> 8;
  const int nwg = nxg * MBLK;
  int raw = blockIdx.x + nxg * blockIdx.y;
  int bid = (raw & 7) * (nwg >> 3) + (raw >> 3);
  const int by = bid % MBLK, bx = bid / MBLK;   // m fastest -> B-panel L2 reuse
  const int m0g = by * 256;
  int e = 0;
#pragma unroll
  for (int i = 1; i < Ee; ++i) e += (m0g >= offs[i]) ? 1 : 0;
  const int ce = cnt[e];
  const int mloc = m0g - offs[e];
  if (mloc >= ce) return;
  const int n0 = bx * 256;

  __shared__ __align__(16) unsigned short AsF[4 * 8192];  // 64 KiB
  __shared__ __align__(16) unsigned short BsF[4 * 8192];  // 64 KiB

  const int tid = threadIdx.x;
  const int w = tid >> 6, lane = tid & 63;
  const int g = lane >> 4, r16 = lane & 15;
  const int wr = w >> 2, wc = w & 3;

  constexpr int KT1 = Ff / 32;  // 32
  const unsigned short* aU0 = xg + (size_t)(2 * by + 0) * KT1 * 4096;
  const unsigned short* aU1 = xg + (size_t)(2 * by + 1) * KT1 * 4096;
  const unsigned short* bU0 = W1P + ((size_t)e * (Hc >> 7) + 2 * bx + 0) * KT1 * 4096;
  const unsigned short* bU1 = W1P + ((size_t)e * (Hc >> 7) + 2 * bx + 1) * KT1 * 4096;

  f32x4 acc[8][4] = {};
  auto STAGE = [&](int buf, int kt) {
    unsigned short* aD = AsF + buf * 8192 + w * 1024;
    unsigned short* bD = BsF + buf * 8192 + w * 1024;
    // per-lane GLOBAL source (+lane*8 shorts = 16 B/lane); LDS dest is wave-uniform base
    const unsigned short* aS = (w < 4 ? aU0 : aU1) + (size_t)kt * 4096 + (w & 3) * 1024 + lane * 8;
    const unsigned short* bS = (w < 4 ? bU0 : bU1) + (size_t)kt * 4096 + (w & 3) * 1024 + lane * 8;
    gl_lds16(aS,       aD);
    gl_lds16(aS + 512, aD + 512);
    gl_lds16(bS,       bD);
    gl_lds16(bS + 512, bD + 512);
  };
  STAGE(0, 0); STAGE(1, 1); STAGE(2, 2);
#pragma unroll 1
  for (int t = 0; t < KT1; ++t) {
    const int rem = KT1 - t;
    if (rem >= 3)      asm volatile("s_waitcnt vmcnt(8)" ::: "memory");
    else if (rem == 2) asm volatile("s_waitcnt vmcnt(4)" ::: "memory");
    else               asm volatile("s_waitcnt vmcnt(0)" ::: "memory");
    __builtin_amdgcn_s_barrier();
    asm volatile("" ::: "memory");
    const int buf = t & 3;
    const unsigned short* ar = AsF + buf * 8192 + (wr * 4 + g) * 1024 + r16 * 8;
    const unsigned short* br = BsF + buf * 8192 + ((wc >> 1) * 4 + g) * 1024 + ((wc & 1) * 64 + r16) * 8;
    bf16x8 af[8], bfr[4];
#pragma unroll
    for (int f = 0; f < 8; ++f) af[f] = *reinterpret_cast<const bf16x8*>(ar + f * 128);
#pragma unroll
    for (int n = 0; n < 4; ++n) bfr[n] = *reinterpret_cast<const bf16x8*>(br + n * 128);
    asm volatile("s_waitcnt lgkmcnt(0)" ::: "memory");
    __builtin_amdgcn_sched_barrier(0);
    if (t + 3 < KT1) STAGE((t + 3) & 3, t + 3);
    __builtin_amdgcn_s_setprio(1);
#pragma unroll
    for (int m = 0; m < 8; ++m)
#pragma unroll
      for (int n = 0; n < 4; ++n)
        acc[m][n] = __builtin_amdgcn_mfma_f32_16x16x32_bf16(af[m], bfr[n], acc[m][n], 0, 0, 0);
    __builtin_amdgcn_s_setprio(0);
    asm volatile("" ::: "memory");
  }
  // epilogue: write hp in packed-A layout, unit = 2*by + wr
  const int KT2 = Hc >> 5;
  unsigned short* hb = hp + (size_t)(2 * by + wr) * KT2 * 4096;
#pragma unroll
  for (int n = 0; n < 4; ++n) {
    const int col = n0 + wc * 64 + n * 16 + r16;
    const float bias = b1[(size_t)e * Hh + (size_t)c * Hc + col];
    unsigned short* hcol = hb + ((size_t)(col >> 5) * 4 + ((col >> 3) & 3)) * 1024 + (col & 7);
#pragma unroll
    for (int m = 0; m < 8; ++m)
#pragma unroll
      for (int r = 0; r < 4; ++r) {
        const int row128 = m * 16 + g * 4 + r;
        const int row = wr * 128 + row128;
        if (mloc + row < ce)
          hcol[row128 * 8] = bf16bits(gelu_tanh(acc[m][n][r] + bias));
      }
  }
}

// ==== GEMM2: 256^2 tile, 8 waves, depth-4 pipeline, K-split, atomic combine ====
__global__ __launch_bounds__(512, 2) void gemm2_mfma(
    const unsigned short* __restrict__ hp, const unsigned short* __restrict__ W2P,
    const float* __restrict__ b2, const int* __restrict__ cnt,
    const int* __restrict__ offs, const int* __restrict__ list,
    const float* __restrict__ wlist, float* __restrict__ out,
    int Hc, int kLen, int ksplit, int biasC) {
  const int nxg = Ff >> 8;   // 4
  const int nwg = nxg * MBLK * ksplit;
  int raw = blockIdx.x + nxg * (blockIdx.y + MBLK * blockIdx.z);
  int bid = (raw & 7) * (nwg >> 3) + (raw >> 3);
  const int by = bid % MBLK;
  const int rest = bid / MBLK;
  const int bx = rest % nxg;
  const int bz = rest / nxg;

  const int m0g = by * 256;
  int e = 0;
#pragma unroll
  for (int i = 1; i < Ee; ++i) e += (m0g >= offs[i]) ? 1 : 0;
  const int ce = cnt[e];
  const int mloc = m0g - offs[e];
  if (mloc >= ce) return;
  const int n0 = bx * 256;

  __shared__ __align__(16) unsigned short AsF[4 * 8192];
  __shared__ __align__(16) unsigned short BsF[4 * 8192];

  const int tid = threadIdx.x;
  const int w = tid >> 6, lane = tid & 63;
  const int g = lane >> 4, r16 = lane & 15;
  const int wr = w >> 2, wc = w & 3;

  const int KT2 = Hc >> 5;
  const int ktOff = (bz * kLen) >> 5;
  const int NT = kLen >> 5;
  const unsigned short* aU0 = hp + ((size_t)(2 * by + 0) * KT2 + ktOff) * 4096;
  const unsigned short* aU1 = hp + ((size_t)(2 * by + 1) * KT2 + ktOff) * 4096;
  const unsigned short* bU0 = W2P + (((size_t)e * 8 + 2 * bx + 0) * KT2 + ktOff) * 4096;
  const unsigned short* bU1 = W2P + (((size_t)e * 8 + 2 * bx + 1) * KT2 + ktOff) * 4096;

  f32x4 acc[8][4] = {};
  auto STAGE = [&](int buf, int kt) {
    unsigned short* aD = AsF + buf * 8192 + w * 1024;
    unsigned short* bD = BsF + buf * 8192 + w * 1024;
    const unsigned short* aS = (w < 4 ? aU0 : aU1) + (size_t)kt * 4096 + (w & 3) * 1024 + lane * 8;
    const unsigned short* bS = (w < 4 ? bU0 : bU1) + (size_t)kt * 4096 + (w & 3) * 1024 + lane * 8;
    gl_lds16(aS,       aD);
    gl_lds16(aS + 512, aD + 512);
    gl_lds16(bS,       bD);
    gl_lds16(bS + 512, bD + 512);
  };
  STAGE(0, 0);
  if (NT > 1) STAGE(1, 1);
  if (NT > 2) STAGE(2, 2);
#pragma unroll 1
  for (int t = 0; t < NT; ++t) {
    const int rem = NT - t;
    if (rem >= 3)      asm volatile("s_waitcnt vmcnt(8)" ::: "memory");
    else if (rem == 2) asm volatile("s_waitcnt vmcnt(4)" ::: "memory");
    else               asm volatile("s_waitcnt vmcnt(0)" ::: "memory");
    __builtin_amdgcn_s_barrier();
    asm volatile("" ::: "memory");
    const int buf = t & 3;
    const unsigned short* ar = AsF + buf * 8192 + (wr * 4 + g) * 1024 + r16 * 8;
    const unsigned short* br = BsF + buf * 8192 + ((wc >> 1) * 4 + g) * 1024 + ((wc & 1) * 64 + r16) * 8;
    bf16x8 af[8], bfr[4];
#pragma unroll
    for (int f = 0; f < 8; ++f) af[f] = *reinterpret_cast<const bf16x8*>(ar + f * 128);
#pragma unroll
    for (int n = 0; n < 4; ++n) bfr[n] = *reinterpret_cast<const bf16x8*>(br + n * 128);
    asm volatile("s_waitcnt lgkmcnt(0)" ::: "memory");
    __builtin_amdgcn_sched_barrier(0);
    if (t + 3 < NT) STAGE((t + 3) & 3, t + 3);
    __builtin_amdgcn_s_setprio(1);
#pragma unroll
    for (int m = 0; m < 8; ++m)
#pragma unroll
      for (int n = 0; n < 4; ++n)
        acc[m][n] = __builtin_amdgcn_mfma_f32_16x16x32_bf16(af[m], bfr[n], acc[m][n], 0, 0, 0);
    __builtin_amdgcn_s_setprio(0);
    asm volatile("" ::: "memory");
  }
  const bool addBias = (biasC != 0) && (bz == 0);
#pragma unroll
  for (int m = 0; m < 8; ++m)
#pragma unroll
    for (int r = 0; r < 4; ++r) {
      const int row = wr * 128 + m * 16 + g * 4 + r;
      if (mloc + row >= ce) continue;
      const int token = list[e * T + mloc + row];
      const float wgt = wlist[e * T + mloc + row];
      float* op = out + (size_t)token * Ff;
#pragma unroll
      for (int n = 0; n < 4; ++n) {
        const int col = n0 + wc * 64 + n * 16 + r16;
        float v = acc[m][n][r];
        if (addBias) v += b2[(size_t)e * Ff + col];
        atomicAdd(&op[col], wgt * v);
      }
    }
}

extern "C" void kernel_launch(void* const* d_in, const int* in_sizes, int n_in,
                              void* d_out, int out_size, void* d_ws, size_t ws_size,
                              hipStream_t stream) {
  const float* x  = (const float*)d_in[0];
  const float* Wg = (const float*)d_in[1];
  const float* bg = (const float*)d_in[2];
  const float* W1 = (const float*)d_in[3];
  const float* b1 = (const float*)d_in[4];
  const float* W2 = (const float*)d_in[5];
  const float* b2 = (const float*)d_in[6];
  float* out = (float*)d_out;

  // fixed = ctrl + lists + xg(80 units x 1024k bf16); per-Hc-unit = W1P + W2P + hp
  const size_t fixed = 1024 + 2 * (size_t)T * Ee * 4 + (size_t)MB128 * 128 * Ff * 2;
  int Hc = 4096;
  while (Hc > 256 && fixed + (size_t)Hc * 53248 > ws_size) Hc >>= 1;
  const int nchunk = Hh / Hc;
  const int kLen = (Hc / 4 >= 128) ? Hc / 4 : 128;
  const int ksplit = Hc / kLen;

  char* p = (char*)d_ws;
  int*   cnt   = (int*)p;            p += 512;
  int*   offs  = (int*)p;            p += 512;
  int*   list  = (int*)p;            p += (size_t)T * Ee * 4;
  float* wlist = (float*)p;          p += (size_t)T * Ee * 4;
  unsigned short* xg  = (unsigned short*)p;  p += (size_t)MB128 * 128 * Ff * 2;
  unsigned short* W1P = (unsigned short*)p;  p += (size_t)Ee * Hc * Ff * 2;
  unsigned short* W2P = (unsigned short*)p;  p += (size_t)Ee * Ff * Hc * 2;
  unsigned short* hp  = (unsigned short*)p;  // MB128*128 x Hc x 2

  hipMemsetAsync(d_out, 0, (size_t)out_size * sizeof(float), stream);
  hipMemsetAsync(cnt, 0, 64, stream);

  gating_kernel<<<T / 4, 256, 0, stream>>>(x, Wg, bg, cnt, list, wlist);
  prefix_kernel<<<1, 64, 0, stream>>>(cnt, offs);
  pack_x_kernel<<<dim3(Ff / 32, MB128), 256, 0, stream>>>(x, cnt, offs, list, xg);

  for (int c = 0; c < nchunk; ++c) {
    pack_w_kernel<<<dim3(Hc / 128, Ff / 32, Ee), 256, 0, stream>>>(
        W1 + (size_t)c * Hc, W1P, Hh, (size_t)Ff * Hh, (size_t)Hc * Ff, Ff / 32);
    pack_w_kernel<<<dim3(Ff / 128, Hc / 32, Ee), 256, 0, stream>>>(
        W2 + (size_t)c * Hc * Ff, W2P, Ff, (size_t)Hh * Ff, (size_t)Ff * Hc, Hc / 32);
    gemm1_mfma<<<dim3(Hc / 256, MBLK), 512, 0, stream>>>(
        xg, W1P, b1, cnt, offs, hp, Hc, c);
    gemm2_mfma<<<dim3(Ff / 256, MBLK, ksplit), 512, 0, stream>>>(
        hp, W2P, b2, cnt, offs, list, wlist, out, Hc, kLen, ksplit,
        c == nchunk - 1 ? 1 : 0);
  }
}

// Round 11
// 566.946 us; speedup vs baseline: 1.0446x; 1.0446x over previous
//
#include <hip/hip_runtime.h>
#include <hip/hip_bf16.h>

// Problem constants: B=4, S=1024, F=1024, E=8, K=2, H=4*F=4096
constexpr int Ff = 1024;
constexpr int Ee = 8;
constexpr int Hh = 4096;
constexpr int T  = 4096;        // B*S tokens
constexpr int MB = 80;          // 128-row m-units over padded row space (<=10240 rows)

typedef short     bf16x8 __attribute__((ext_vector_type(8)));
typedef float     f32x4  __attribute__((ext_vector_type(4)));
typedef unsigned short u16x8 __attribute__((ext_vector_type(8)));

__device__ __forceinline__ float gelu_tanh(float v) {
  const float c = 0.7978845608028654f;  // sqrt(2/pi)
  float t = tanhf(c * (v + 0.044715f * v * v * v));
  return 0.5f * v * (1.0f + t);
}

__device__ __forceinline__ unsigned short bf16bits(float f) {
  __hip_bfloat16 h = __float2bfloat16(f);
  return *reinterpret_cast<unsigned short*>(&h);
}

__device__ __forceinline__ void gl_lds16(const void* g, void* l) {
  __builtin_amdgcn_global_load_lds(
      (const __attribute__((address_space(1))) unsigned int*)g,
      (__attribute__((address_space(3))) unsigned int*)l, 16, 0, 0);
}

// ---------------- Gating (fp32, exact routing) ----------------
__global__ __launch_bounds__(256) void gating_kernel(
    const float* __restrict__ x, const float* __restrict__ Wg,
    const float* __restrict__ bg, int* __restrict__ cnt,
    int* __restrict__ list, float* __restrict__ wlist) {
  const int wave = threadIdx.x >> 6;
  const int lane = threadIdx.x & 63;
  const int t = blockIdx.x * 4 + wave;
  float acc[Ee] = {0.f,0.f,0.f,0.f,0.f,0.f,0.f,0.f};
  const float* xrow = x + (size_t)t * Ff;
  for (int f0 = 0; f0 < Ff; f0 += 64) {
    float xv = xrow[f0 + lane];
    const float* wrow = Wg + (size_t)(f0 + lane) * Ee;
    float4 w0 = *reinterpret_cast<const float4*>(wrow);
    float4 w1 = *reinterpret_cast<const float4*>(wrow + 4);
    acc[0] += xv * w0.x; acc[1] += xv * w0.y;
    acc[2] += xv * w0.z; acc[3] += xv * w0.w;
    acc[4] += xv * w1.x; acc[5] += xv * w1.y;
    acc[6] += xv * w1.z; acc[7] += xv * w1.w;
  }
#pragma unroll
  for (int e = 0; e < Ee; ++e) {
#pragma unroll
    for (int off = 32; off; off >>= 1) acc[e] += __shfl_xor(acc[e], off);
  }
  if (lane == 0) {
    float l[Ee], m = -1e30f;
#pragma unroll
    for (int e = 0; e < Ee; ++e) { l[e] = acc[e] + bg[e]; m = fmaxf(m, l[e]); }
    float p[Ee], Z = 0.f;
#pragma unroll
    for (int e = 0; e < Ee; ++e) { p[e] = expf(l[e] - m); Z += p[e]; }
#pragma unroll
    for (int e = 0; e < Ee; ++e) p[e] /= Z;
    int i1 = 0; float p1 = p[0];
#pragma unroll
    for (int e = 1; e < Ee; ++e) if (p[e] > p1) { p1 = p[e]; i1 = e; }
    int i2 = -1; float p2 = -1e30f;
#pragma unroll
    for (int e = 0; e < Ee; ++e) if (e != i1 && p[e] > p2) { p2 = p[e]; i2 = e; }
    float denom = p1 + p2 + 1e-8f;
    int pos = atomicAdd(&cnt[i1], 1);
    list[i1 * T + pos] = t; wlist[i1 * T + pos] = p1 / denom;
    pos = atomicAdd(&cnt[i2], 1);
    list[i2 * T + pos] = t; wlist[i2 * T + pos] = p2 / denom;
  }
}

// 128-aligned expert row offsets (padded flattened row space)
__global__ void prefix_kernel(const int* __restrict__ cnt, int* __restrict__ offs) {
  if (threadIdx.x == 0) {
    int s = 0;
    for (int e = 0; e < Ee; ++e) { offs[e] = s; s += (cnt[e] + 127) & ~127; }
    offs[Ee] = s;
  }
}

// ---- pack_w: src fp32 [K][N] (stride sN) -> dst bf16 units [NB][KT][4][128][8]
__global__ __launch_bounds__(256) void pack_w_kernel(
    const float* __restrict__ src, unsigned short* __restrict__ dst,
    int sN, size_t s_estride, size_t d_estride, int KT) {
  const int e  = blockIdx.z;
  const int nb = blockIdx.x;
  const int kt = blockIdx.y;
  __shared__ float Ts[128][33];
  const int t = threadIdx.x;
  const float* sb = src + (size_t)e * s_estride + (size_t)(kt * 32) * sN + nb * 128;
  {
    const int row = t >> 5;
    const int cc  = (t & 31) * 4;
#pragma unroll
    for (int i = 0; i < 4; ++i) {
      float4 v = *reinterpret_cast<const float4*>(sb + (size_t)(row + 8 * i) * sN + cc);
      Ts[cc + 0][row + 8 * i] = v.x;
      Ts[cc + 1][row + 8 * i] = v.y;
      Ts[cc + 2][row + 8 * i] = v.z;
      Ts[cc + 3][row + 8 * i] = v.w;
    }
  }
  __syncthreads();
  unsigned short* db = dst + (size_t)e * d_estride + ((size_t)nb * KT + kt) * 4096;
#pragma unroll
  for (int j = 0; j < 2; ++j) {
    const int idx = t + 256 * j;
    const int col = idx & 127, kb = idx >> 7;
    u16x8 o;
#pragma unroll
    for (int q = 0; q < 8; ++q) o[q] = bf16bits(Ts[col][kb * 8 + q]);
    *reinterpret_cast<u16x8*>(db + kb * 1024 + col * 8) = o;
  }
}

// ---- pack_x: gather tokens -> xg[mb][kt][4][128][8], zero-filled pads
__global__ __launch_bounds__(256) void pack_x_kernel(
    const float* __restrict__ x, const int* __restrict__ cnt,
    const int* __restrict__ offs, const int* __restrict__ list,
    unsigned short* __restrict__ xg) {
  const int kt = blockIdx.x;
  const int mb = blockIdx.y;
  const int t = threadIdx.x;
  const int m0g = mb * 128;
  int e = 0;
#pragma unroll
  for (int i = 1; i < Ee; ++i) e += (m0g >= offs[i]) ? 1 : 0;
  const int ce = cnt[e];
  const int row = t >> 1, half = t & 1;
  const int mloc = m0g - offs[e] + row;
  const bool valid = (mloc >= 0) && (mloc < ce);
  const int token = valid ? list[e * T + mloc] : 0;
  const float* sp = x + (size_t)token * Ff + kt * 32 + half * 16;
  u16x8 o0, o1;
#pragma unroll
  for (int i = 0; i < 2; ++i) {
    float4 v = valid ? *reinterpret_cast<const float4*>(sp + i * 4)
                     : make_float4(0.f, 0.f, 0.f, 0.f);
    o0[i * 4 + 0] = bf16bits(v.x); o0[i * 4 + 1] = bf16bits(v.y);
    o0[i * 4 + 2] = bf16bits(v.z); o0[i * 4 + 3] = bf16bits(v.w);
  }
#pragma unroll
  for (int i = 2; i < 4; ++i) {
    float4 v = valid ? *reinterpret_cast<const float4*>(sp + i * 4)
                     : make_float4(0.f, 0.f, 0.f, 0.f);
    o1[(i - 2) * 4 + 0] = bf16bits(v.x); o1[(i - 2) * 4 + 1] = bf16bits(v.y);
    o1[(i - 2) * 4 + 2] = bf16bits(v.z); o1[(i - 2) * 4 + 3] = bf16bits(v.w);
  }
  unsigned short* db = xg + ((size_t)mb * (Ff / 32) + kt) * 4096 + row * 8;
  *reinterpret_cast<u16x8*>(db + (half * 2 + 0) * 1024) = o0;
  *reinterpret_cast<u16x8*>(db + (half * 2 + 1) * 1024) = o1;
}

// ======== GEMM1: 128^2 tile, 4 waves, BK=64, dbuf counted, band-supertiled ========
__global__ __launch_bounds__(256, 2) void gemm1_mfma(
    const unsigned short* __restrict__ xg, const unsigned short* __restrict__ W1P,
    const float* __restrict__ b1, const int* __restrict__ cnt,
    const int* __restrict__ offs, unsigned short* __restrict__ hp, int Hc, int c) {
  const int nxg = Hc >> 7;
  const int nwg = nxg * MB;
  const int raw = blockIdx.x;
  int bid = (raw & 7) * (nwg >> 3) + (raw >> 3);   // XCD gets contiguous range
  const int bw = (nxg >= 4) ? 4 : nxg;             // n-band width
  const int band = bid / (MB * bw);
  const int r2 = bid % (MB * bw);
  const int by = r2 / bw;
  const int bx = band * bw + (r2 % bw);

  const int m0g = by * 128;
  int e = 0;
#pragma unroll
  for (int i = 1; i < Ee; ++i) e += (m0g >= offs[i]) ? 1 : 0;
  const int ce = cnt[e];
  const int mloc = m0g - offs[e];
  if (mloc >= ce) return;
  const int n0 = bx * 128;

  __shared__ __align__(16) unsigned short AsF[2 * 8192];  // 32 KiB
  __shared__ __align__(16) unsigned short BsF[2 * 8192];  // 32 KiB

  const int tid = threadIdx.x;
  const int w = tid >> 6, lane = tid & 63;
  const int g = lane >> 4, r16 = lane & 15;
  const int wr = w >> 1, wc = w & 1;

  constexpr int KT1 = Ff / 32;   // 32 packed kt-units
  constexpr int NT  = Ff / 64;   // 16 K-tiles of 64
  const unsigned short* aU = xg  + (size_t)by * KT1 * 4096;
  const unsigned short* bU = W1P + (size_t)(e * nxg + bx) * KT1 * 4096;

  f32x4 acc[4][4] = {};
  auto STAGE = [&](int buf, int t) {
    const unsigned short* aS = aU + (size_t)t * 8192 + w * 2048 + lane * 8;
    const unsigned short* bS = bU + (size_t)t * 8192 + w * 2048 + lane * 8;
    unsigned short* aD = AsF + buf * 8192 + w * 2048;
    unsigned short* bD = BsF + buf * 8192 + w * 2048;
#pragma unroll
    for (int q = 0; q < 4; ++q) {
      gl_lds16(aS + q * 512, aD + q * 512);
      gl_lds16(bS + q * 512, bD + q * 512);
    }
  };
  STAGE(0, 0);
  int cur = 0;
#pragma unroll 1
  for (int t = 0; t < NT; ++t) {
    if (t + 1 < NT) {
      STAGE(cur ^ 1, t + 1);
      asm volatile("s_waitcnt vmcnt(8)" ::: "memory");
    } else {
      asm volatile("s_waitcnt vmcnt(0)" ::: "memory");
    }
    __builtin_amdgcn_s_barrier();
    asm volatile("" ::: "memory");
    bf16x8 af[4][2], bfr[4][2];
#pragma unroll
    for (int s = 0; s < 2; ++s)
#pragma unroll
      for (int i = 0; i < 4; ++i) {
        af[i][s]  = *reinterpret_cast<const bf16x8*>(
            AsF + cur * 8192 + s * 4096 + g * 1024 + (wr * 64 + i * 16 + r16) * 8);
        bfr[i][s] = *reinterpret_cast<const bf16x8*>(
            BsF + cur * 8192 + s * 4096 + g * 1024 + (wc * 64 + i * 16 + r16) * 8);
      }
    asm volatile("s_waitcnt lgkmcnt(0)" ::: "memory");
    __builtin_amdgcn_sched_barrier(0);
    __builtin_amdgcn_s_setprio(1);
#pragma unroll
    for (int s = 0; s < 2; ++s)
#pragma unroll
      for (int mi = 0; mi < 4; ++mi)
#pragma unroll
        for (int ni = 0; ni < 4; ++ni)
          acc[mi][ni] = __builtin_amdgcn_mfma_f32_16x16x32_bf16(
              af[mi][s], bfr[ni][s], acc[mi][ni], 0, 0, 0);
    __builtin_amdgcn_s_setprio(0);
    asm volatile("" ::: "memory");
    __builtin_amdgcn_s_barrier();
    cur ^= 1;
  }
  // epilogue: write hp in packed-A layout (unit = by)
  const int KT2 = Hc >> 5;
  unsigned short* hb = hp + (size_t)by * KT2 * 4096;
#pragma unroll
  for (int ni = 0; ni < 4; ++ni) {
    const int col = n0 + wc * 64 + ni * 16 + r16;
    const float bias = b1[(size_t)e * Hh + (size_t)c * Hc + col];
    unsigned short* hcol = hb + ((size_t)(col >> 5) * 4 + ((col >> 3) & 3)) * 1024 + (col & 7);
#pragma unroll
    for (int mi = 0; mi < 4; ++mi)
#pragma unroll
      for (int r = 0; r < 4; ++r) {
        const int row = wr * 64 + mi * 16 + g * 4 + r;
        if (mloc + row < ce)
          hcol[row * 8] = bf16bits(gelu_tanh(acc[mi][ni][r] + bias));
      }
  }
}

// ==== GEMM2: 128^2 tile, 4 waves, BK=64, dbuf counted, n-fastest chunks, K-split=2 ====
__global__ __launch_bounds__(256, 2) void gemm2_mfma(
    const unsigned short* __restrict__ hp, const unsigned short* __restrict__ W2P,
    const float* __restrict__ b2, const int* __restrict__ cnt,
    const int* __restrict__ offs, const int* __restrict__ list,
    const float* __restrict__ wlist, float* __restrict__ out,
    int Hc, int kLen, int ksplit, int biasC) {
  constexpr int nxg = Ff >> 7;   // 8
  const int nwg = nxg * MB * ksplit;
  const int raw = blockIdx.x;
  int bid = (raw & 7) * (nwg >> 3) + (raw >> 3);
  const int bx = bid % nxg;      // n fastest -> A-panel reused by co-resident n-blocks
  const int rest = bid / nxg;
  const int by = rest % MB;
  const int bz = rest / MB;

  const int m0g = by * 128;
  int e = 0;
#pragma unroll
  for (int i = 1; i < Ee; ++i) e += (m0g >= offs[i]) ? 1 : 0;
  const int ce = cnt[e];
  const int mloc = m0g - offs[e];
  if (mloc >= ce) return;
  const int n0 = bx * 128;

  __shared__ __align__(16) unsigned short AsF[2 * 8192];
  __shared__ __align__(16) unsigned short BsF[2 * 8192];

  const int tid = threadIdx.x;
  const int w = tid >> 6, lane = tid & 63;
  const int g = lane >> 4, r16 = lane & 15;
  const int wr = w >> 1, wc = w & 1;

  const int KT2 = Hc >> 5;
  const int ktOff = (bz * kLen) >> 5;
  const int NT = kLen >> 6;      // K-tiles of 64
  const unsigned short* aU = hp  + ((size_t)by * KT2 + ktOff) * 4096;
  const unsigned short* bU = W2P + ((size_t)(e * nxg + bx) * KT2 + ktOff) * 4096;

  f32x4 acc[4][4] = {};
  auto STAGE = [&](int buf, int t) {
    const unsigned short* aS = aU + (size_t)t * 8192 + w * 2048 + lane * 8;
    const unsigned short* bS = bU + (size_t)t * 8192 + w * 2048 + lane * 8;
    unsigned short* aD = AsF + buf * 8192 + w * 2048;
    unsigned short* bD = BsF + buf * 8192 + w * 2048;
#pragma unroll
    for (int q = 0; q < 4; ++q) {
      gl_lds16(aS + q * 512, aD + q * 512);
      gl_lds16(bS + q * 512, bD + q * 512);
    }
  };
  STAGE(0, 0);
  int cur = 0;
#pragma unroll 1
  for (int t = 0; t < NT; ++t) {
    if (t + 1 < NT) {
      STAGE(cur ^ 1, t + 1);
      asm volatile("s_waitcnt vmcnt(8)" ::: "memory");
    } else {
      asm volatile("s_waitcnt vmcnt(0)" ::: "memory");
    }
    __builtin_amdgcn_s_barrier();
    asm volatile("" ::: "memory");
    bf16x8 af[4][2], bfr[4][2];
#pragma unroll
    for (int s = 0; s < 2; ++s)
#pragma unroll
      for (int i = 0; i < 4; ++i) {
        af[i][s]  = *reinterpret_cast<const bf16x8*>(
            AsF + cur * 8192 + s * 4096 + g * 1024 + (wr * 64 + i * 16 + r16) * 8);
        bfr[i][s] = *reinterpret_cast<const bf16x8*>(
            BsF + cur * 8192 + s * 4096 + g * 1024 + (wc * 64 + i * 16 + r16) * 8);
      }
    asm volatile("s_waitcnt lgkmcnt(0)" ::: "memory");
    __builtin_amdgcn_sched_barrier(0);
    __builtin_amdgcn_s_setprio(1);
#pragma unroll
    for (int s = 0; s < 2; ++s)
#pragma unroll
      for (int mi = 0; mi < 4; ++mi)
#pragma unroll
        for (int ni = 0; ni < 4; ++ni)
          acc[mi][ni] = __builtin_amdgcn_mfma_f32_16x16x32_bf16(
              af[mi][s], bfr[ni][s], acc[mi][ni], 0, 0, 0);
    __builtin_amdgcn_s_setprio(0);
    asm volatile("" ::: "memory");
    __builtin_amdgcn_s_barrier();
    cur ^= 1;
  }
  const bool addBias = (biasC != 0) && (bz == 0);
#pragma unroll
  for (int mi = 0; mi < 4; ++mi)
#pragma unroll
    for (int r = 0; r < 4; ++r) {
      const int row = wr * 64 + mi * 16 + g * 4 + r;
      if (mloc + row >= ce) continue;
      const int token = list[e * T + mloc + row];
      const float wgt = wlist[e * T + mloc + row];
      float* op = out + (size_t)token * Ff;
#pragma unroll
      for (int ni = 0; ni < 4; ++ni) {
        const int col = n0 + wc * 64 + ni * 16 + r16;
        float v = acc[mi][ni][r];
        if (addBias) v += b2[(size_t)e * Ff + col];
        atomicAdd(&op[col], wgt * v);
      }
    }
}

extern "C" void kernel_launch(void* const* d_in, const int* in_sizes, int n_in,
                              void* d_out, int out_size, void* d_ws, size_t ws_size,
                              hipStream_t stream) {
  const float* x  = (const float*)d_in[0];
  const float* Wg = (const float*)d_in[1];
  const float* bg = (const float*)d_in[2];
  const float* W1 = (const float*)d_in[3];
  const float* b1 = (const float*)d_in[4];
  const float* W2 = (const float*)d_in[5];
  const float* b2 = (const float*)d_in[6];
  float* out = (float*)d_out;

  // fixed = ctrl + lists + xg(80 units x 1024 k, bf16); per-Hc-unit = W1P + W2P + hp
  const size_t fixed = 1024 + 2 * (size_t)T * Ee * 4 + (size_t)MB * 128 * Ff * 2;
  int Hc = 4096;
  while (Hc > 256 && fixed + (size_t)Hc * 53248 > ws_size) Hc >>= 1;
  const int nchunk = Hh / Hc;
  const int ksplit = 2;
  const int kLen = Hc / ksplit;   // >= 128

  char* p = (char*)d_ws;
  int*   cnt   = (int*)p;            p += 512;
  int*   offs  = (int*)p;            p += 512;
  int*   list  = (int*)p;            p += (size_t)T * Ee * 4;
  float* wlist = (float*)p;          p += (size_t)T * Ee * 4;
  unsigned short* xg  = (unsigned short*)p;  p += (size_t)MB * 128 * Ff * 2;
  unsigned short* W1P = (unsigned short*)p;  p += (size_t)Ee * Hc * Ff * 2;
  unsigned short* W2P = (unsigned short*)p;  p += (size_t)Ee * Ff * Hc * 2;
  unsigned short* hp  = (unsigned short*)p;  // MB*128 x Hc x 2

  hipMemsetAsync(d_out, 0, (size_t)out_size * sizeof(float), stream);
  hipMemsetAsync(cnt, 0, 64, stream);

  gating_kernel<<<T / 4, 256, 0, stream>>>(x, Wg, bg, cnt, list, wlist);
  prefix_kernel<<<1, 64, 0, stream>>>(cnt, offs);
  pack_x_kernel<<<dim3(Ff / 32, MB), 256, 0, stream>>>(x, cnt, offs, list, xg);

  for (int c = 0; c < nchunk; ++c) {
    pack_w_kernel<<<dim3(Hc / 128, Ff / 32, Ee), 256, 0, stream>>>(
        W1 + (size_t)c * Hc, W1P, Hh, (size_t)Ff * Hh, (size_t)Hc * Ff, Ff / 32);
    pack_w_kernel<<<dim3(Ff / 128, Hc / 32, Ee), 256, 0, stream>>>(
        W2 + (size_t)c * Hc * Ff, W2P, Ff, (size_t)Hh * Ff, (size_t)Ff * Hc, Hc / 32);
    gemm1_mfma<<<(Hc / 128) * MB, 256, 0, stream>>>(
        xg, W1P, b1, cnt, offs, hp, Hc, c);
    gemm2_mfma<<<(Ff / 128) * MB * ksplit, 256, 0, stream>>>(
        hp, W2P, b2, cnt, offs, list, wlist, out, Hc, kLen, ksplit,
        c == nchunk - 1 ? 1 : 0);
  }
}

// Round 12
// 474.150 us; speedup vs baseline: 1.2490x; 1.1957x over previous
//
#include <hip/hip_runtime.h>
#include <hip/hip_bf16.h>

// Problem constants: B=4, S=1024, F=1024, E=8, K=2, H=4*F=4096
constexpr int Ff = 1024;
constexpr int Ee = 8;
constexpr int Hh = 4096;
constexpr int T  = 4096;        // B*S tokens
constexpr int MB = 80;          // 128-row m-units over padded row space (<=10240 rows)

typedef short     bf16x8 __attribute__((ext_vector_type(8)));
typedef float     f32x4  __attribute__((ext_vector_type(4)));
typedef unsigned short u16x8 __attribute__((ext_vector_type(8)));

__device__ __forceinline__ float gelu_fast(float v) {
  // gelu_tanh(v) = v * sigmoid(2*z), z = sqrt(2/pi)*(v + 0.044715 v^3)
  const float c2 = 2.0f * 0.7978845608028654f;
  float z2 = c2 * (v + 0.044715f * v * v * v);
  return v / (1.0f + __expf(-z2));
}

__device__ __forceinline__ unsigned short bf16bits(float f) {
  __hip_bfloat16 h = __float2bfloat16(f);
  return *reinterpret_cast<unsigned short*>(&h);
}

__device__ __forceinline__ void gl_lds16(const void* g, void* l) {
  __builtin_amdgcn_global_load_lds(
      (const __attribute__((address_space(1))) unsigned int*)g,
      (__attribute__((address_space(3))) unsigned int*)l, 16, 0, 0);
}

// ---------------- Gating (fp32, exact routing) ----------------
__global__ __launch_bounds__(256) void gating_kernel(
    const float* __restrict__ x, const float* __restrict__ Wg,
    const float* __restrict__ bg, int* __restrict__ cnt,
    int* __restrict__ list, float* __restrict__ wlist) {
  const int wave = threadIdx.x >> 6;
  const int lane = threadIdx.x & 63;
  const int t = blockIdx.x * 4 + wave;
  float acc[Ee] = {0.f,0.f,0.f,0.f,0.f,0.f,0.f,0.f};
  const float* xrow = x + (size_t)t * Ff;
  for (int f0 = 0; f0 < Ff; f0 += 64) {
    float xv = xrow[f0 + lane];
    const float* wrow = Wg + (size_t)(f0 + lane) * Ee;
    float4 w0 = *reinterpret_cast<const float4*>(wrow);
    float4 w1 = *reinterpret_cast<const float4*>(wrow + 4);
    acc[0] += xv * w0.x; acc[1] += xv * w0.y;
    acc[2] += xv * w0.z; acc[3] += xv * w0.w;
    acc[4] += xv * w1.x; acc[5] += xv * w1.y;
    acc[6] += xv * w1.z; acc[7] += xv * w1.w;
  }
#pragma unroll
  for (int e = 0; e < Ee; ++e) {
#pragma unroll
    for (int off = 32; off; off >>= 1) acc[e] += __shfl_xor(acc[e], off);
  }
  if (lane == 0) {
    float l[Ee], m = -1e30f;
#pragma unroll
    for (int e = 0; e < Ee; ++e) { l[e] = acc[e] + bg[e]; m = fmaxf(m, l[e]); }
    float p[Ee], Z = 0.f;
#pragma unroll
    for (int e = 0; e < Ee; ++e) { p[e] = expf(l[e] - m); Z += p[e]; }
#pragma unroll
    for (int e = 0; e < Ee; ++e) p[e] /= Z;
    int i1 = 0; float p1 = p[0];
#pragma unroll
    for (int e = 1; e < Ee; ++e) if (p[e] > p1) { p1 = p[e]; i1 = e; }
    int i2 = -1; float p2 = -1e30f;
#pragma unroll
    for (int e = 0; e < Ee; ++e) if (e != i1 && p[e] > p2) { p2 = p[e]; i2 = e; }
    float denom = p1 + p2 + 1e-8f;
    int pos = atomicAdd(&cnt[i1], 1);
    list[i1 * T + pos] = t; wlist[i1 * T + pos] = p1 / denom;
    pos = atomicAdd(&cnt[i2], 1);
    list[i2 * T + pos] = t; wlist[i2 * T + pos] = p2 / denom;
  }
}

// 128-aligned expert row offsets (padded flattened row space)
__global__ void prefix_kernel(const int* __restrict__ cnt, int* __restrict__ offs) {
  if (threadIdx.x == 0) {
    int s = 0;
    for (int e = 0; e < Ee; ++e) { offs[e] = s; s += (cnt[e] + 127) & ~127; }
    offs[Ee] = s;
  }
}

// ---- pack_w: src fp32 [K][N] (stride sN) -> dst bf16 units [NB][KT][4][128][8]
__global__ __launch_bounds__(256) void pack_w_kernel(
    const float* __restrict__ src, unsigned short* __restrict__ dst,
    int sN, size_t s_estride, size_t d_estride, int KT) {
  const int e  = blockIdx.z;
  const int nb = blockIdx.x;
  const int kt = blockIdx.y;
  __shared__ float Ts[128][33];
  const int t = threadIdx.x;
  const float* sb = src + (size_t)e * s_estride + (size_t)(kt * 32) * sN + nb * 128;
  {
    const int row = t >> 5;
    const int cc  = (t & 31) * 4;
#pragma unroll
    for (int i = 0; i < 4; ++i) {
      float4 v = *reinterpret_cast<const float4*>(sb + (size_t)(row + 8 * i) * sN + cc);
      Ts[cc + 0][row + 8 * i] = v.x;
      Ts[cc + 1][row + 8 * i] = v.y;
      Ts[cc + 2][row + 8 * i] = v.z;
      Ts[cc + 3][row + 8 * i] = v.w;
    }
  }
  __syncthreads();
  unsigned short* db = dst + (size_t)e * d_estride + ((size_t)nb * KT + kt) * 4096;
#pragma unroll
  for (int j = 0; j < 2; ++j) {
    const int idx = t + 256 * j;
    const int col = idx & 127, kb = idx >> 7;
    u16x8 o;
#pragma unroll
    for (int q = 0; q < 8; ++q) o[q] = bf16bits(Ts[col][kb * 8 + q]);
    *reinterpret_cast<u16x8*>(db + kb * 1024 + col * 8) = o;
  }
}

// ---- pack_x: gather tokens -> xg[mb][kt][4][128][8], zero-filled pads
__global__ __launch_bounds__(256) void pack_x_kernel(
    const float* __restrict__ x, const int* __restrict__ cnt,
    const int* __restrict__ offs, const int* __restrict__ list,
    unsigned short* __restrict__ xg) {
  const int kt = blockIdx.x;
  const int mb = blockIdx.y;
  const int t = threadIdx.x;
  const int m0g = mb * 128;
  int e = 0;
#pragma unroll
  for (int i = 1; i < Ee; ++i) e += (m0g >= offs[i]) ? 1 : 0;
  const int ce = cnt[e];
  const int row = t >> 1, half = t & 1;
  const int mloc = m0g - offs[e] + row;
  const bool valid = (mloc >= 0) && (mloc < ce);
  const int token = valid ? list[e * T + mloc] : 0;
  const float* sp = x + (size_t)token * Ff + kt * 32 + half * 16;
  u16x8 o0, o1;
#pragma unroll
  for (int i = 0; i < 2; ++i) {
    float4 v = valid ? *reinterpret_cast<const float4*>(sp + i * 4)
                     : make_float4(0.f, 0.f, 0.f, 0.f);
    o0[i * 4 + 0] = bf16bits(v.x); o0[i * 4 + 1] = bf16bits(v.y);
    o0[i * 4 + 2] = bf16bits(v.z); o0[i * 4 + 3] = bf16bits(v.w);
  }
#pragma unroll
  for (int i = 2; i < 4; ++i) {
    float4 v = valid ? *reinterpret_cast<const float4*>(sp + i * 4)
                     : make_float4(0.f, 0.f, 0.f, 0.f);
    o1[(i - 2) * 4 + 0] = bf16bits(v.x); o1[(i - 2) * 4 + 1] = bf16bits(v.y);
    o1[(i - 2) * 4 + 2] = bf16bits(v.z); o1[(i - 2) * 4 + 3] = bf16bits(v.w);
  }
  unsigned short* db = xg + ((size_t)mb * (Ff / 32) + kt) * 4096 + row * 8;
  *reinterpret_cast<u16x8*>(db + (half * 2 + 0) * 1024) = o0;
  *reinterpret_cast<u16x8*>(db + (half * 2 + 1) * 1024) = o1;
}

// ======== GEMM1: 128^2 tile, 4 waves, BK=32, depth-3 packed pipeline, 3 blk/CU ========
__global__ __launch_bounds__(256, 3) void gemm1_mfma(
    const unsigned short* __restrict__ xg, const unsigned short* __restrict__ W1P,
    const float* __restrict__ b1, const int* __restrict__ cnt,
    const int* __restrict__ offs, unsigned short* __restrict__ hp, int Hc, int c) {
  const int nxg = Hc >> 7;
  const int nwg = nxg * MB;
  const int raw = blockIdx.x;
  int bid = (raw & 7) * (nwg >> 3) + (raw >> 3);   // XCD gets contiguous range
  const int bw = (nxg >= 4) ? 4 : nxg;             // n-band width
  const int band = bid / (MB * bw);
  const int r2 = bid % (MB * bw);
  const int by = r2 / bw;
  const int bx = band * bw + (r2 % bw);

  const int m0g = by * 128;
  int e = 0;
#pragma unroll
  for (int i = 1; i < Ee; ++i) e += (m0g >= offs[i]) ? 1 : 0;
  const int ce = cnt[e];
  const int mloc = m0g - offs[e];
  if (mloc >= ce) return;
  const int n0 = bx * 128;

  __shared__ __align__(16) unsigned short AsF[3 * 4096];  // 24 KiB
  __shared__ __align__(16) unsigned short BsF[3 * 4096];  // 24 KiB

  const int tid = threadIdx.x;
  const int w = tid >> 6, lane = tid & 63;
  const int g = lane >> 4, r16 = lane & 15;
  const int wr = w >> 1, wc = w & 1;

  constexpr int NT = Ff / 32;    // 32 packed kt-units
  const unsigned short* aU = xg  + (size_t)by * NT * 4096;
  const unsigned short* bU = W1P + (size_t)(e * nxg + bx) * NT * 4096;

  f32x4 acc[4][4] = {};
  auto STAGE = [&](int buf, int kt) {
    const unsigned short* aS = aU + (size_t)kt * 4096 + w * 1024 + lane * 8;
    const unsigned short* bS = bU + (size_t)kt * 4096 + w * 1024 + lane * 8;
    unsigned short* aD = AsF + buf * 4096 + w * 1024;
    unsigned short* bD = BsF + buf * 4096 + w * 1024;
    gl_lds16(aS,       aD);
    gl_lds16(aS + 512, aD + 512);
    gl_lds16(bS,       bD);
    gl_lds16(bS + 512, bD + 512);
  };
  STAGE(0, 0); STAGE(1, 1); STAGE(2, 2);
  int cur = 0;
#pragma unroll 1
  for (int t = 0; t < NT; ++t) {
    const int rem = NT - t;
    if (rem >= 3)      asm volatile("s_waitcnt vmcnt(8)" ::: "memory");
    else if (rem == 2) asm volatile("s_waitcnt vmcnt(4)" ::: "memory");
    else               asm volatile("s_waitcnt vmcnt(0)" ::: "memory");
    __builtin_amdgcn_s_barrier();
    asm volatile("" ::: "memory");
    bf16x8 af[4], bfr[4];
#pragma unroll
    for (int i = 0; i < 4; ++i) {
      af[i]  = *reinterpret_cast<const bf16x8*>(
          AsF + cur * 4096 + g * 1024 + (wr * 64 + i * 16 + r16) * 8);
      bfr[i] = *reinterpret_cast<const bf16x8*>(
          BsF + cur * 4096 + g * 1024 + (wc * 64 + i * 16 + r16) * 8);
    }
    asm volatile("s_waitcnt lgkmcnt(0)" ::: "memory");
    __builtin_amdgcn_sched_barrier(0);
    __builtin_amdgcn_s_barrier();
    if (t + 3 < NT) STAGE(cur, t + 3);   // (t+3)%3 == cur
    __builtin_amdgcn_s_setprio(1);
#pragma unroll
    for (int mi = 0; mi < 4; ++mi)
#pragma unroll
      for (int ni = 0; ni < 4; ++ni)
        acc[mi][ni] = __builtin_amdgcn_mfma_f32_16x16x32_bf16(
            af[mi], bfr[ni], acc[mi][ni], 0, 0, 0);
    __builtin_amdgcn_s_setprio(0);
    asm volatile("" ::: "memory");
    cur = (cur == 2) ? 0 : cur + 1;
  }
  // epilogue: write hp in packed-A layout (unit = by)
  const int KT2 = Hc >> 5;
  unsigned short* hb = hp + (size_t)by * KT2 * 4096;
#pragma unroll
  for (int ni = 0; ni < 4; ++ni) {
    const int col = n0 + wc * 64 + ni * 16 + r16;
    const float bias = b1[(size_t)e * Hh + (size_t)c * Hc + col];
    unsigned short* hcol = hb + ((size_t)(col >> 5) * 4 + ((col >> 3) & 3)) * 1024 + (col & 7);
#pragma unroll
    for (int mi = 0; mi < 4; ++mi)
#pragma unroll
      for (int r = 0; r < 4; ++r) {
        const int row = wr * 64 + mi * 16 + g * 4 + r;
        if (mloc + row < ce)
          hcol[row * 8] = bf16bits(gelu_fast(acc[mi][ni][r] + bias));
      }
  }
}

// ==== GEMM2: 128^2 tile, 4 waves, BK=32, depth-3 packed pipeline, K-split=2 ====
__global__ __launch_bounds__(256, 3) void gemm2_mfma(
    const unsigned short* __restrict__ hp, const unsigned short* __restrict__ W2P,
    const float* __restrict__ b2, const int* __restrict__ cnt,
    const int* __restrict__ offs, const int* __restrict__ list,
    const float* __restrict__ wlist, float* __restrict__ out,
    int Hc, int kLen, int ksplit, int biasC) {
  constexpr int nxg = Ff >> 7;   // 8
  const int nwg = nxg * MB * ksplit;
  const int raw = blockIdx.x;
  int bid = (raw & 7) * (nwg >> 3) + (raw >> 3);
  const int bx = bid % nxg;      // n fastest -> A-panel reused by co-resident n-blocks
  const int rest = bid / nxg;
  const int by = rest % MB;
  const int bz = rest / MB;

  const int m0g = by * 128;
  int e = 0;
#pragma unroll
  for (int i = 1; i < Ee; ++i) e += (m0g >= offs[i]) ? 1 : 0;
  const int ce = cnt[e];
  const int mloc = m0g - offs[e];
  if (mloc >= ce) return;
  const int n0 = bx * 128;

  __shared__ __align__(16) unsigned short AsF[3 * 4096];
  __shared__ __align__(16) unsigned short BsF[3 * 4096];

  const int tid = threadIdx.x;
  const int w = tid >> 6, lane = tid & 63;
  const int g = lane >> 4, r16 = lane & 15;
  const int wr = w >> 1, wc = w & 1;

  const int KT2 = Hc >> 5;
  const int ktOff = (bz * kLen) >> 5;
  const int NT = kLen >> 5;
  const unsigned short* aU = hp  + ((size_t)by * KT2 + ktOff) * 4096;
  const unsigned short* bU = W2P + ((size_t)(e * nxg + bx) * KT2 + ktOff) * 4096;

  f32x4 acc[4][4] = {};
  auto STAGE = [&](int buf, int kt) {
    const unsigned short* aS = aU + (size_t)kt * 4096 + w * 1024 + lane * 8;
    const unsigned short* bS = bU + (size_t)kt * 4096 + w * 1024 + lane * 8;
    unsigned short* aD = AsF + buf * 4096 + w * 1024;
    unsigned short* bD = BsF + buf * 4096 + w * 1024;
    gl_lds16(aS,       aD);
    gl_lds16(aS + 512, aD + 512);
    gl_lds16(bS,       bD);
    gl_lds16(bS + 512, bD + 512);
  };
  STAGE(0, 0);
  if (NT > 1) STAGE(1, 1);
  if (NT > 2) STAGE(2, 2);
  int cur = 0;
#pragma unroll 1
  for (int t = 0; t < NT; ++t) {
    const int rem = NT - t;
    if (rem >= 3)      asm volatile("s_waitcnt vmcnt(8)" ::: "memory");
    else if (rem == 2) asm volatile("s_waitcnt vmcnt(4)" ::: "memory");
    else               asm volatile("s_waitcnt vmcnt(0)" ::: "memory");
    __builtin_amdgcn_s_barrier();
    asm volatile("" ::: "memory");
    bf16x8 af[4], bfr[4];
#pragma unroll
    for (int i = 0; i < 4; ++i) {
      af[i]  = *reinterpret_cast<const bf16x8*>(
          AsF + cur * 4096 + g * 1024 + (wr * 64 + i * 16 + r16) * 8);
      bfr[i] = *reinterpret_cast<const bf16x8*>(
          BsF + cur * 4096 + g * 1024 + (wc * 64 + i * 16 + r16) * 8);
    }
    asm volatile("s_waitcnt lgkmcnt(0)" ::: "memory");
    __builtin_amdgcn_sched_barrier(0);
    __builtin_amdgcn_s_barrier();
    if (t + 3 < NT) STAGE(cur, t + 3);
    __builtin_amdgcn_s_setprio(1);
#pragma unroll
    for (int mi = 0; mi < 4; ++mi)
#pragma unroll
      for (int ni = 0; ni < 4; ++ni)
        acc[mi][ni] = __builtin_amdgcn_mfma_f32_16x16x32_bf16(
            af[mi], bfr[ni], acc[mi][ni], 0, 0, 0);
    __builtin_amdgcn_s_setprio(0);
    asm volatile("" ::: "memory");
    cur = (cur == 2) ? 0 : cur + 1;
  }
  const bool addBias = (biasC != 0) && (bz == 0);
#pragma unroll
  for (int mi = 0; mi < 4; ++mi)
#pragma unroll
    for (int r = 0; r < 4; ++r) {
      const int row = wr * 64 + mi * 16 + g * 4 + r;
      if (mloc + row >= ce) continue;
      const int token = list[e * T + mloc + row];
      const float wgt = wlist[e * T + mloc + row];
      float* op = out + (size_t)token * Ff;
#pragma unroll
      for (int ni = 0; ni < 4; ++ni) {
        const int col = n0 + wc * 64 + ni * 16 + r16;
        float v = acc[mi][ni][r];
        if (addBias) v += b2[(size_t)e * Ff + col];
        atomicAdd(&op[col], wgt * v);
      }
    }
}

extern "C" void kernel_launch(void* const* d_in, const int* in_sizes, int n_in,
                              void* d_out, int out_size, void* d_ws, size_t ws_size,
                              hipStream_t stream) {
  const float* x  = (const float*)d_in[0];
  const float* Wg = (const float*)d_in[1];
  const float* bg = (const float*)d_in[2];
  const float* W1 = (const float*)d_in[3];
  const float* b1 = (const float*)d_in[4];
  const float* W2 = (const float*)d_in[5];
  const float* b2 = (const float*)d_in[6];
  float* out = (float*)d_out;

  // fixed = ctrl + lists + xg(80 units x 1024 k, bf16); per-Hc-unit = W1P + W2P + hp
  const size_t fixed = 1024 + 2 * (size_t)T * Ee * 4 + (size_t)MB * 128 * Ff * 2;
  int Hc = 4096;
  while (Hc > 256 && fixed + (size_t)Hc * 53248 > ws_size) Hc >>= 1;
  const int nchunk = Hh / Hc;
  const int ksplit = 2;
  const int kLen = Hc / ksplit;   // >= 128

  char* p = (char*)d_ws;
  int*   cnt   = (int*)p;            p += 512;
  int*   offs  = (int*)p;            p += 512;
  int*   list  = (int*)p;            p += (size_t)T * Ee * 4;
  float* wlist = (float*)p;          p += (size_t)T * Ee * 4;
  unsigned short* xg  = (unsigned short*)p;  p += (size_t)MB * 128 * Ff * 2;
  unsigned short* W1P = (unsigned short*)p;  p += (size_t)Ee * Hc * Ff * 2;
  unsigned short* W2P = (unsigned short*)p;  p += (size_t)Ee * Ff * Hc * 2;
  unsigned short* hp  = (unsigned short*)p;  // MB*128 x Hc x 2

  hipMemsetAsync(d_out, 0, (size_t)out_size * sizeof(float), stream);
  hipMemsetAsync(cnt, 0, 64, stream);

  gating_kernel<<<T / 4, 256, 0, stream>>>(x, Wg, bg, cnt, list, wlist);
  prefix_kernel<<<1, 64, 0, stream>>>(cnt, offs);
  pack_x_kernel<<<dim3(Ff / 32, MB), 256, 0, stream>>>(x, cnt, offs, list, xg);

  for (int c = 0; c < nchunk; ++c) {
    pack_w_kernel<<<dim3(Hc / 128, Ff / 32, Ee), 256, 0, stream>>>(
        W1 + (size_t)c * Hc, W1P, Hh, (size_t)Ff * Hh, (size_t)Hc * Ff, Ff / 32);
    pack_w_kernel<<<dim3(Ff / 128, Hc / 32, Ee), 256, 0, stream>>>(
        W2 + (size_t)c * Hc * Ff, W2P, Ff, (size_t)Hh * Ff, (size_t)Ff * Hc, Hc / 32);
    gemm1_mfma<<<(Hc / 128) * MB, 256, 0, stream>>>(
        xg, W1P, b1, cnt, offs, hp, Hc, c);
    gemm2_mfma<<<(Ff / 128) * MB * ksplit, 256, 0, stream>>>(
        hp, W2P, b2, cnt, offs, list, wlist, out, Hc, kLen, ksplit,
        c == nchunk - 1 ? 1 : 0);
  }
}